// Round 6
// baseline (2674.049 us; speedup 1.0000x reference)
//
#include <hip/hip_runtime.h>
#include <hip/hip_bf16.h>
#include <stdint.h>

#define BB 64
#define TT 32
#define HID 512
#define XD  512
#define NV  10000

#define GRID   512
#define NCELL  128
#define VB     32
#define NLOG   313       // ceil(10000/32)
#define LOGB   128       // first logits block
#define NORMB  441       // first normalize block (441..504)

typedef __bf16 bf16x8 __attribute__((ext_vector_type(8)));
typedef float  f32x4  __attribute__((ext_vector_type(4)));

// XOR swizzle in units of 8 bf16 (16B) within each 8-row stripe.
// Applied on BOTH write and read sides (reg-staged LDS, rule #21 ok).
__device__ inline int SWZ(int row, int k) { return k ^ ((row & 7) << 3); }

__device__ inline void split2(float w, __bf16& hi, __bf16& lo) {
  hi = (__bf16)w;
  lo = (__bf16)(w - (float)hi);
}

__device__ inline unsigned long long shflxor64(unsigned long long v, int m) {
  unsigned lo = (unsigned)(v & 0xFFFFFFFFull);
  unsigned hi = (unsigned)(v >> 32);
  lo = __shfl_xor(lo, m);
  hi = __shfl_xor(hi, m);
  return ((unsigned long long)hi << 32) | lo;
}

// monotonic packing of (logit, vocab index); larger u64 = larger logit,
// ties broken toward SMALLER index (matches jnp.argmax first-occurrence).
__device__ inline unsigned long long packkey(float f, int v) {
  unsigned ub = __float_as_uint(f);
  unsigned key = (ub & 0x80000000u) ? ~ub : (ub | 0x80000000u);
  return ((unsigned long long)key << 32) | (unsigned)(0xFFFFFFFFu - (unsigned)v);
}

// RELAXED poll (no per-iteration cache inv), ONE acquire load at the end.
__device__ inline void spin_until(int* ctr, int target) {
  if (threadIdx.x == 0) {
    while (__hip_atomic_load(ctr, __ATOMIC_RELAXED, __HIP_MEMORY_SCOPE_AGENT) < target)
      __builtin_amdgcn_s_sleep(2);
    (void)__hip_atomic_load(ctr, __ATOMIC_ACQUIRE, __HIP_MEMORY_SCOPE_AGENT); // 1 inv
  }
  __syncthreads();
}

// __syncthreads() drains all threads' stores (vmcnt(0) before s_barrier);
// ONE release fetch_add (one L2 writeback) publishes them.
__device__ inline void mark_done(int* ctr) {
  __syncthreads();
  if (threadIdx.x == 0)
    __hip_atomic_fetch_add(ctr, 1, __ATOMIC_RELEASE, __HIP_MEMORY_SCOPE_AGENT);
}

struct Params {
  const float *x, *emb;
  const float *Whi, *Whf, *Who, *Whz;
  const float *Wxi, *Wxf, *Wxo, *Wxz;
  const float *bi, *bfg, *bo, *bz;
  const float *W_lin, *b_lin;
  float* out;
  __bf16 *h_hi, *h_lo;
  float* c_ws;
  unsigned long long* gmax;   // [TT][BB] per-step, zeroed in k_init
  float* gsum;                // [TT][BB]
  int *cd, *ld;               // cell_done[TT], logits_done[TT]
};

// cell: W resident for all 32 steps (16 gate-cols x K=1024, hi/lo)
struct SMCell { __bf16 Ch[16][1040]; __bf16 Cl[16][1040]; float pre[64][17]; };
// logits: W[t] tile resident (32 vocab cols x K=512, hi/lo)
struct SMLog  { __bf16 Bh[32][520];  __bf16 Bl[32][520]; };
union SMU { SMCell c; SMLog l; };

__global__ __launch_bounds__(256) void k_init(
    const float* __restrict__ h0, const float* __restrict__ c0,
    __bf16* __restrict__ h_hi, __bf16* __restrict__ h_lo,
    float* __restrict__ c_ws,
    unsigned long long* __restrict__ gmax, float* __restrict__ gsum,
    int* __restrict__ ctrs) {
  int i = blockIdx.x * 256 + threadIdx.x;   // grid = 128 blocks = BB*HID threads
  float h = h0[i];
  __bf16 hi, lo; split2(h, hi, lo);
  h_hi[i] = hi; h_lo[i] = lo;
  c_ws[i] = c0[i];
  if (blockIdx.x == 0 && threadIdx.x < 64) ctrs[threadIdx.x] = 0;   // cd[32]+ld[32]
  if (blockIdx.x >= 1 && blockIdx.x <= 8) {
    int j = (blockIdx.x - 1) * 256 + threadIdx.x;                   // 0..2047
    gmax[j] = 0ULL;
    gsum[j] = 0.f;
  }
}

__global__ __launch_bounds__(256, 2) void k_main(Params p) {
  __shared__ SMU sm;
  const int bid = blockIdx.x, tid = threadIdx.x;
  const int lane = tid & 63, wid = tid >> 6;

  // ======================= CELL blocks 0..127 =======================
  if (bid < NCELL) {
    const int n0 = bid * 4;
    const float* WH[4] = {p.Whi, p.Whf, p.Who, p.Whz};
    const float* WX[4] = {p.Wxi, p.Wxf, p.Wxo, p.Wxz};

    // one-time stage: 16 rows (gate g, col j) x K=1024 (h:0..511, x:512..1023)
    #pragma unroll
    for (int i2 = 0; i2 < 16; i2++) {
      int e = tid + i2 * 256;          // 0..4095 ; e = k*4 + g
      int k = e >> 2, g = e & 3;
      const float* src = (k < HID) ? (WH[g] + (size_t)k * HID + n0)
                                   : (WX[g] + (size_t)(k - HID) * HID + n0);
      float4 w = *(const float4*)src;
      #pragma unroll
      for (int j = 0; j < 4; j++) {
        int rrow = g * 4 + j;
        __bf16 hi, lo; split2(((const float*)&w)[j], hi, lo);
        sm.c.Ch[rrow][SWZ(rrow, k)] = hi;
        sm.c.Cl[rrow][SWZ(rrow, k)] = lo;
      }
    }
    __syncthreads();

    const int row  = wid * 16 + (lane & 15);
    const int brow = lane & 15;

    for (int t = 0; t < TT; t++) {
      const int pc = t & 1, po = pc ^ 1;
      if (t > 0) spin_until(&p.ld[t - 1], NLOG);

      const __bf16* hr  = p.h_hi + (size_t)pc * BB * HID;
      const __bf16* hrl = p.h_lo + (size_t)pc * BB * HID;
      __bf16* hw  = p.h_hi + (size_t)po * BB * HID;
      __bf16* hwl = p.h_lo + (size_t)po * BB * HID;

      const float* xrow;
      if (t == 0) {
        xrow = p.x + (size_t)row * TT * XD;          // x[row][0][:]
      } else {
        unsigned long long mk = p.gmax[(size_t)(t - 1) * BB + row];
        int tok = (int)(0xFFFFFFFFu - (unsigned)(mk & 0xFFFFFFFFull));
        xrow = p.emb + (size_t)tok * XD;
      }

      f32x4 accA = {0.f, 0.f, 0.f, 0.f};
      f32x4 accB = {0.f, 0.f, 0.f, 0.f};

      // h-part: ks 0..15, barrier-free (W resident in LDS)
      #pragma unroll
      for (int ks = 0; ks < 16; ks++) {
        int kk = ks * 32 + (lane >> 4) * 8;
        bf16x8 ah = *(const bf16x8*)(hr  + (size_t)row * HID + kk);
        bf16x8 al = *(const bf16x8*)(hrl + (size_t)row * HID + kk);
        bf16x8 bh = *(const bf16x8*)&sm.c.Ch[brow][SWZ(brow, kk)];
        bf16x8 bl = *(const bf16x8*)&sm.c.Cl[brow][SWZ(brow, kk)];
        accA = __builtin_amdgcn_mfma_f32_16x16x32_bf16(ah, bh, accA, 0, 0, 0);
        accB = __builtin_amdgcn_mfma_f32_16x16x32_bf16(ah, bl, accB, 0, 0, 0);
        accB = __builtin_amdgcn_mfma_f32_16x16x32_bf16(al, bh, accB, 0, 0, 0);
        accA = __builtin_amdgcn_mfma_f32_16x16x32_bf16(al, bl, accA, 0, 0, 0);
      }
      // x-part: ks 16..31
      #pragma unroll
      for (int ks = 16; ks < 32; ks++) {
        int kk = ks * 32 + (lane >> 4) * 8;          // 512..1016
        const float* xp = xrow + (kk - HID);
        float4 w0 = *(const float4*)(xp);
        float4 w1 = *(const float4*)(xp + 4);
        bf16x8 ah, al;
        #pragma unroll
        for (int j = 0; j < 4; j++) {
          __bf16 hi, lo;
          split2(((const float*)&w0)[j], hi, lo); ah[j] = hi; al[j] = lo;
          split2(((const float*)&w1)[j], hi, lo); ah[4 + j] = hi; al[4 + j] = lo;
        }
        bf16x8 bh = *(const bf16x8*)&sm.c.Ch[brow][SWZ(brow, kk)];
        bf16x8 bl = *(const bf16x8*)&sm.c.Cl[brow][SWZ(brow, kk)];
        accA = __builtin_amdgcn_mfma_f32_16x16x32_bf16(ah, bh, accA, 0, 0, 0);
        accB = __builtin_amdgcn_mfma_f32_16x16x32_bf16(ah, bl, accB, 0, 0, 0);
        accB = __builtin_amdgcn_mfma_f32_16x16x32_bf16(al, bh, accB, 0, 0, 0);
        accA = __builtin_amdgcn_mfma_f32_16x16x32_bf16(al, bl, accA, 0, 0, 0);
      }

      #pragma unroll
      for (int j = 0; j < 4; j++)
        sm.c.pre[wid * 16 + (lane >> 4) * 4 + j][lane & 15] = accA[j] + accB[j];
      __syncthreads();

      {
        int rloc = tid >> 2, q = tid & 3;
        int n = n0 + q;
        float pi = sm.c.pre[rloc][q]      + p.bi[n];
        float pf = sm.c.pre[rloc][4 + q]  + p.bfg[n];
        float pq = sm.c.pre[rloc][8 + q]  + p.bo[n];
        float pz = sm.c.pre[rloc][12 + q] + p.bz[n];
        float ig = 1.f / (1.f + expf(-pi));
        float fg = 1.f / (1.f + expf(-pf));
        float og = 1.f / (1.f + expf(-pq));
        float zg = tanhf(pz);
        float cp = p.c_ws[rloc * HID + n];
        float cn = ig * zg + fg * cp;
        p.c_ws[rloc * HID + n] = cn;
        p.out[(size_t)BB * TT * NV + (size_t)rloc * TT * HID + (size_t)t * HID + n] = cn;
        float hn = og * tanhf(cn);
        __bf16 hh, hl; split2(hn, hh, hl);
        hw [rloc * HID + n] = hh;
        hwl[rloc * HID + n] = hl;
      }
      mark_done(&p.cd[t]);   // barrier also protects pre[] across steps
    }
    return;
  }

  // ======================= LOGITS blocks 128..440 =======================
  if (bid < NORMB) {
    const int lb = bid - LOGB;
    const int v0 = lb * VB;
    const int row = wid * 16 + (lane & 15);

    // stage W tile: 32 vocab cols x 512 k, fp32 -> hi/lo bf16 LDS (swizzled)
    auto stageW = [&](int widx) {
      const float* W = p.W_lin + (size_t)widx * HID * NV;
      #pragma unroll
      for (int i2 = 0; i2 < 16; i2++) {
        int e = tid + i2 * 256;          // 0..4095 ; e = k*8 + pp
        int k = e >> 3, pp = e & 7;
        // reads past v=9999 stay inside the W row (widx<=30), masked later
        float4 w = *(const float4*)(W + (size_t)k * NV + v0 + pp * 4);
        #pragma unroll
        for (int j = 0; j < 4; j++) {
          int rrow = pp * 4 + j;
          __bf16 hi, lo; split2(((const float*)&w)[j], hi, lo);
          sm.l.Bh[rrow][SWZ(rrow, k)] = hi;
          sm.l.Bl[rrow][SWZ(rrow, k)] = lo;
        }
      }
    };

    stageW(0);   // logits(0) uses lidx=0

    for (int t = 0; t < TT; t++) {
      const int po = (t & 1) ^ 1;
      spin_until(&p.cd[t], NCELL);   // barrier also makes staged LDS visible

      const __bf16* hhi = p.h_hi + (size_t)po * BB * HID;
      const __bf16* hlo = p.h_lo + (size_t)po * BB * HID;

      f32x4 acc[2][2] = {};
      #pragma unroll
      for (int ks = 0; ks < 16; ks++) {
        int kk = ks * 32 + (lane >> 4) * 8;
        bf16x8 ah = *(const bf16x8*)(hhi + (size_t)row * HID + kk);
        bf16x8 al = *(const bf16x8*)(hlo + (size_t)row * HID + kk);
        #pragma unroll
        for (int vt = 0; vt < 2; vt++) {
          int rrow = vt * 16 + (lane & 15);
          bf16x8 bh = *(const bf16x8*)&sm.l.Bh[rrow][SWZ(rrow, kk)];
          bf16x8 bl = *(const bf16x8*)&sm.l.Bl[rrow][SWZ(rrow, kk)];
          acc[vt][0] = __builtin_amdgcn_mfma_f32_16x16x32_bf16(ah, bh, acc[vt][0], 0, 0, 0);
          acc[vt][1] = __builtin_amdgcn_mfma_f32_16x16x32_bf16(ah, bl, acc[vt][1], 0, 0, 0);
          acc[vt][1] = __builtin_amdgcn_mfma_f32_16x16x32_bf16(al, bh, acc[vt][1], 0, 0, 0);
          acc[vt][0] = __builtin_amdgcn_mfma_f32_16x16x32_bf16(al, bl, acc[vt][0], 0, 0, 0);
        }
      }

      const int lidx = (t == 0) ? 0 : t - 1;
      const float* brow_p = p.b_lin + (size_t)lidx * NV;
      float rsum[4] = {0.f, 0.f, 0.f, 0.f};
      unsigned long long rmax[4] = {0ULL, 0ULL, 0ULL, 0ULL};

      #pragma unroll
      for (int vt = 0; vt < 2; vt++) {
        int v = v0 + vt * 16 + (lane & 15);
        if (v < NV) {
          float bb = brow_p[v];
          #pragma unroll
          for (int j = 0; j < 4; j++) {
            int r = wid * 16 + (lane >> 4) * 4 + j;
            float logit = acc[vt][0][j] + acc[vt][1][j] + bb;
            float e = expf(logit);          // no max-subtract: |logit| small
            p.out[(size_t)r * TT * NV + (size_t)t * NV + v] = e;
            rsum[j] += e;
            unsigned long long pk = packkey(logit, v);
            if (pk > rmax[j]) rmax[j] = pk;
          }
        }
      }

      #pragma unroll
      for (int off = 1; off < 16; off <<= 1) {
        #pragma unroll
        for (int j = 0; j < 4; j++) {
          rsum[j] += __shfl_xor(rsum[j], off);
          unsigned long long o = shflxor64(rmax[j], off);
          if (o > rmax[j]) rmax[j] = o;
        }
      }
      if ((lane & 15) == 0) {
        #pragma unroll
        for (int j = 0; j < 4; j++) {
          int r = wid * 16 + (lane >> 4) * 4 + j;
          atomicAdd(&p.gsum[(size_t)t * BB + r], rsum[j]);
          atomicMax(&p.gmax[(size_t)t * BB + r], rmax[j]);
        }
      }
      mark_done(&p.ld[t]);   // barrier also protects LDS before re-staging

      if (t < TT - 1) stageW(t);   // logits(t+1) uses lidx=t; overlaps cell(t+1)
    }
    return;
  }

  // ======================= NORMALIZE blocks 441..504 =======================
  if (bid < NORMB + BB) {
    const int r = bid - NORMB;
    // warm the embedding table into LLC while step 0 runs (off critical path)
    {
      float s = 0.f;
      const float4* Ep = (const float4*)p.emb;
      for (int i = r * 256 + tid; i < NV * XD / 4; i += BB * 256) {
        float4 v = Ep[i]; s += v.x + v.y + v.z + v.w;
      }
      asm volatile("" :: "v"(s));   // keep warm-up loads live
    }
    for (int t = 0; t < TT; t++) {
      spin_until(&p.ld[t], NLOG);
      float inv = 1.0f / p.gsum[(size_t)t * BB + r];
      float4* y4 = (float4*)(p.out + (size_t)r * TT * NV + (size_t)t * NV);
      for (int i = tid; i < NV / 4; i += 256) {
        float4 v = y4[i];
        v.x *= inv; v.y *= inv; v.z *= inv; v.w *= inv;
        y4[i] = v;
      }
    }
    return;
  }
  // blocks 505..511 idle
}

extern "C" void kernel_launch(void* const* d_in, const int* in_sizes, int n_in,
                              void* d_out, int out_size, void* d_ws, size_t ws_size,
                              hipStream_t stream) {
  const float* x     = (const float*)d_in[0];
  const float* h0    = (const float*)d_in[1];
  const float* c0    = (const float*)d_in[2];
  const float* W_hi  = (const float*)d_in[3];
  const float* W_xi  = (const float*)d_in[4];
  const float* b_i   = (const float*)d_in[5];
  const float* W_hf  = (const float*)d_in[6];
  const float* W_xf  = (const float*)d_in[7];
  const float* b_f   = (const float*)d_in[8];
  const float* W_ho  = (const float*)d_in[9];
  const float* W_xo  = (const float*)d_in[10];
  const float* b_o   = (const float*)d_in[11];
  const float* W_hz  = (const float*)d_in[12];
  const float* W_xz  = (const float*)d_in[13];
  const float* b_z   = (const float*)d_in[14];
  const float* W_lin = (const float*)d_in[15];
  const float* b_lin = (const float*)d_in[16];
  const float* emb   = (const float*)d_in[17];

  float* out = (float*)d_out;
  char* ws = (char*)d_ws;
  __bf16* h_hi = (__bf16*)ws;                                    // [2][64][512]
  __bf16* h_lo = (__bf16*)(ws + 131072);                         // [2][64][512]
  float*  c_ws = (float*)(ws + 262144);                          // [64][512]
  unsigned long long* gmax = (unsigned long long*)(ws + 393216); // [32][64]
  float*  gsum = (float*)(ws + 409600);                          // [32][64]
  int*    ctrs = (int*)(ws + 417792);                            // cd[32] ld[32]

  k_init<<<128, 256, 0, stream>>>(h0, c0, h_hi, h_lo, c_ws, gmax, gsum, ctrs);

  Params P;
  P.x = x; P.emb = emb;
  P.Whi = W_hi; P.Whf = W_hf; P.Who = W_ho; P.Whz = W_hz;
  P.Wxi = W_xi; P.Wxf = W_xf; P.Wxo = W_xo; P.Wxz = W_xz;
  P.bi = b_i; P.bfg = b_f; P.bo = b_o; P.bz = b_z;
  P.W_lin = W_lin; P.b_lin = b_lin;
  P.out = out;
  P.h_hi = h_hi; P.h_lo = h_lo; P.c_ws = c_ws;
  P.gmax = gmax; P.gsum = gsum;
  P.cd = ctrs; P.ld = ctrs + 32;

  k_main<<<GRID, 256, 0, stream>>>(P);
}

// Round 7
// 2300.942 us; speedup vs baseline: 1.1622x; 1.1622x over previous
//
#include <hip/hip_runtime.h>
#include <hip/hip_bf16.h>
#include <stdint.h>

#define BB 64
#define TT 32
#define HID 512
#define XD  512
#define NV  10000

#define GRID   512
#define NCELL  128
#define VB     32
#define NLOG   313       // ceil(10000/32)
#define LOGB   128       // first logits block
#define NORMB  441       // norm blocks 441..504 (one per batch row)

typedef __bf16 bf16x8 __attribute__((ext_vector_type(8)));
typedef float  f32x4  __attribute__((ext_vector_type(4)));

__device__ inline void split2(float w, __bf16& hi, __bf16& lo) {
  hi = (__bf16)w;
  lo = (__bf16)(w - (float)hi);
}

__device__ inline unsigned long long shflxor64(unsigned long long v, int m) {
  unsigned lo = (unsigned)(v & 0xFFFFFFFFull);
  unsigned hi = (unsigned)(v >> 32);
  lo = __shfl_xor(lo, m);
  hi = __shfl_xor(hi, m);
  return ((unsigned long long)hi << 32) | lo;
}

// monotonic packing of (logit, vocab index); larger u64 = larger logit,
// ties broken toward SMALLER index (matches jnp.argmax first-occurrence).
__device__ inline unsigned long long packkey(float f, int v) {
  unsigned ub = __float_as_uint(f);
  unsigned key = (ub & 0x80000000u) ? ~ub : (ub | 0x80000000u);
  return ((unsigned long long)key << 32) | (unsigned)(0xFFFFFFFFu - (unsigned)v);
}

// RELAXED poll (no per-iteration cache inv), ONE acquire load at the end.
__device__ inline void spin_until(int* ctr, int target) {
  if (threadIdx.x == 0) {
    while (__hip_atomic_load(ctr, __ATOMIC_RELAXED, __HIP_MEMORY_SCOPE_AGENT) < target)
      __builtin_amdgcn_s_sleep(2);
    (void)__hip_atomic_load(ctr, __ATOMIC_ACQUIRE, __HIP_MEMORY_SCOPE_AGENT); // 1 inv
  }
  __syncthreads();
}

// __syncthreads() drains all threads' stores (vmcnt(0) before s_barrier);
// ONE release fetch_add (one L2 writeback) publishes them.
__device__ inline void mark_done(int* ctr) {
  __syncthreads();
  if (threadIdx.x == 0)
    __hip_atomic_fetch_add(ctr, 1, __ATOMIC_RELEASE, __HIP_MEMORY_SCOPE_AGENT);
}

struct Params {
  const float *x, *emb;
  const float *Whi, *Whf, *Who, *Whz;
  const float *Wxi, *Wxf, *Wxo, *Wxz;
  const float *bi, *bfg, *bo, *bz;
  const float *W_lin, *b_lin;
  float* out;
  __bf16 *h_hi, *h_lo;
  float* c_ws;
  float* psum;                 // [2][NLOG][64] per-block partial sums
  unsigned long long* pmax;    // [2][NLOG][64] per-block partial packed max
  unsigned* tok;               // [2][64] argmax token per row
  int *cd, *ld, *rn;           // cell_done[TT], logits_done[TT], reduce_done[TT]
};

// Odd-dword row pitches: cell 1042 bf16 (521 dw = 9 banks/row),
// logits 522 bf16 (261 dw = 5 banks/row) -> conflict-free staging writes,
// <=2-way (free) fragment reads. No XOR swizzle needed.
struct SMCell { __bf16 Ch[16][1042]; __bf16 Cl[16][1042]; float pre[64][17]; };
struct SMLog  { __bf16 Bh[32][522];  __bf16 Bl[32][522]; };
union SMU { SMCell c; SMLog l; };

__global__ __launch_bounds__(256) void k_init(
    const float* __restrict__ h0, const float* __restrict__ c0,
    __bf16* __restrict__ h_hi, __bf16* __restrict__ h_lo,
    float* __restrict__ c_ws, int* __restrict__ ctrs) {
  int i = blockIdx.x * 256 + threadIdx.x;   // grid = 128 blocks = BB*HID threads
  float h = h0[i];
  __bf16 hi, lo; split2(h, hi, lo);
  h_hi[i] = hi; h_lo[i] = lo;
  c_ws[i] = c0[i];
  if (blockIdx.x == 0 && threadIdx.x < 96) ctrs[threadIdx.x] = 0; // cd,ld,rn
}

__global__ __launch_bounds__(256, 2) void k_main(Params p) {
  __shared__ SMU sm;
  __shared__ float red_s[4];
  __shared__ unsigned long long red_m[4];
  __shared__ float bcast_inv;
  const int bid = blockIdx.x, tid = threadIdx.x;
  const int lane = tid & 63, wid = tid >> 6;

  // ======================= CELL blocks 0..127 =======================
  if (bid < NCELL) {
    const int n0 = bid * 4;
    const float* WH[4] = {p.Whi, p.Whf, p.Who, p.Whz};
    const float* WX[4] = {p.Wxi, p.Wxf, p.Wxo, p.Wxz};

    // one-time stage: 16 rows (gate g, col j) x K=1024 (h:0..511, x:512..1023)
    #pragma unroll
    for (int i2 = 0; i2 < 16; i2++) {
      int e = tid + i2 * 256;          // 0..4095 ; e = k*4 + g
      int k = e >> 2, g = e & 3;
      const float* src = (k < HID) ? (WH[g] + (size_t)k * HID + n0)
                                   : (WX[g] + (size_t)(k - HID) * HID + n0);
      float4 w = *(const float4*)src;
      #pragma unroll
      for (int j = 0; j < 4; j++) {
        __bf16 hi, lo; split2(((const float*)&w)[j], hi, lo);
        sm.c.Ch[g * 4 + j][k] = hi;
        sm.c.Cl[g * 4 + j][k] = lo;
      }
    }
    __syncthreads();

    const int row  = wid * 16 + (lane & 15);
    const int brow = lane & 15;

    for (int t = 0; t < TT; t++) {
      const int pc = t & 1, po = pc ^ 1;
      if (t > 0) spin_until(&p.rn[t - 1], BB);   // wait reduce of step t-1

      const __bf16* hr  = p.h_hi + (size_t)pc * BB * HID;
      const __bf16* hrl = p.h_lo + (size_t)pc * BB * HID;
      __bf16* hw  = p.h_hi + (size_t)po * BB * HID;
      __bf16* hwl = p.h_lo + (size_t)po * BB * HID;

      const float* xrow;
      if (t == 0) {
        xrow = p.x + (size_t)row * TT * XD;          // x[row][0][:]
      } else {
        unsigned tokv = p.tok[((t - 1) & 1) * BB + row];
        xrow = p.emb + (size_t)tokv * XD;
      }

      f32x4 accA = {0.f, 0.f, 0.f, 0.f};
      f32x4 accB = {0.f, 0.f, 0.f, 0.f};

      // h-part: ks 0..15, barrier-free (W resident in LDS)
      #pragma unroll
      for (int ks = 0; ks < 16; ks++) {
        int kk = ks * 32 + (lane >> 4) * 8;
        bf16x8 ah = *(const bf16x8*)(hr  + (size_t)row * HID + kk);
        bf16x8 al = *(const bf16x8*)(hrl + (size_t)row * HID + kk);
        bf16x8 bh = *(const bf16x8*)&sm.c.Ch[brow][kk];
        bf16x8 bl = *(const bf16x8*)&sm.c.Cl[brow][kk];
        accA = __builtin_amdgcn_mfma_f32_16x16x32_bf16(ah, bh, accA, 0, 0, 0);
        accB = __builtin_amdgcn_mfma_f32_16x16x32_bf16(ah, bl, accB, 0, 0, 0);
        accB = __builtin_amdgcn_mfma_f32_16x16x32_bf16(al, bh, accB, 0, 0, 0);
        accA = __builtin_amdgcn_mfma_f32_16x16x32_bf16(al, bl, accA, 0, 0, 0);
      }
      // x-part: ks 16..31
      #pragma unroll
      for (int ks = 16; ks < 32; ks++) {
        int kk = ks * 32 + (lane >> 4) * 8;          // 512..1016
        const float* xp = xrow + (kk - HID);
        float4 w0 = *(const float4*)(xp);
        float4 w1 = *(const float4*)(xp + 4);
        bf16x8 ah, al;
        #pragma unroll
        for (int j = 0; j < 4; j++) {
          __bf16 hi, lo;
          split2(((const float*)&w0)[j], hi, lo); ah[j] = hi; al[j] = lo;
          split2(((const float*)&w1)[j], hi, lo); ah[4 + j] = hi; al[4 + j] = lo;
        }
        bf16x8 bh = *(const bf16x8*)&sm.c.Ch[brow][kk];
        bf16x8 bl = *(const bf16x8*)&sm.c.Cl[brow][kk];
        accA = __builtin_amdgcn_mfma_f32_16x16x32_bf16(ah, bh, accA, 0, 0, 0);
        accB = __builtin_amdgcn_mfma_f32_16x16x32_bf16(ah, bl, accB, 0, 0, 0);
        accB = __builtin_amdgcn_mfma_f32_16x16x32_bf16(al, bh, accB, 0, 0, 0);
        accA = __builtin_amdgcn_mfma_f32_16x16x32_bf16(al, bl, accA, 0, 0, 0);
      }

      #pragma unroll
      for (int j = 0; j < 4; j++)
        sm.c.pre[wid * 16 + (lane >> 4) * 4 + j][lane & 15] = accA[j] + accB[j];
      __syncthreads();

      {
        int rloc = tid >> 2, q = tid & 3;
        int n = n0 + q;
        float pi = sm.c.pre[rloc][q]      + p.bi[n];
        float pf = sm.c.pre[rloc][4 + q]  + p.bfg[n];
        float pq = sm.c.pre[rloc][8 + q]  + p.bo[n];
        float pz = sm.c.pre[rloc][12 + q] + p.bz[n];
        float ig = 1.f / (1.f + expf(-pi));
        float fg = 1.f / (1.f + expf(-pf));
        float og = 1.f / (1.f + expf(-pq));
        float zg = tanhf(pz);
        float cp = p.c_ws[rloc * HID + n];
        float cn = ig * zg + fg * cp;
        p.c_ws[rloc * HID + n] = cn;
        p.out[(size_t)BB * TT * NV + (size_t)rloc * TT * HID + (size_t)t * HID + n] = cn;
        float hn = og * tanhf(cn);
        __bf16 hh, hl; split2(hn, hh, hl);
        hw [rloc * HID + n] = hh;
        hwl[rloc * HID + n] = hl;
      }
      mark_done(&p.cd[t]);   // barrier also protects pre[] across steps
    }
    return;
  }

  // ======================= LOGITS blocks 128..440 =======================
  if (bid < NORMB) {
    const int lb = bid - LOGB;
    const int v0 = lb * VB;
    const int row = wid * 16 + (lane & 15);

    float bcar[2];   // b_lin values carried in regs (loaded during stage)
    {
      const float* b0 = p.b_lin;                 // lidx = 0
      bcar[0] = b0[v0 + (lane & 15)];
      bcar[1] = b0[v0 + 16 + (lane & 15)];       // may over-read; masked later
    }

    // stage W tile: 32 vocab cols x 512 k. Issue ALL 16 loads first (T14),
    // then convert+write (padded pitch 522 -> conflict-free writes).
    auto stageW = [&](int widx) {
      const float* W = p.W_lin + (size_t)widx * HID * NV;
      float4 v[16];
      #pragma unroll
      for (int i2 = 0; i2 < 16; i2++) {
        int e = tid + i2 * 256;          // e = k*8 + pp
        int k = e >> 3, pp = e & 7;
        v[i2] = *(const float4*)(W + (size_t)k * NV + v0 + pp * 4);
      }
      const float* bn = p.b_lin + (size_t)widx * NV;
      bcar[0] = bn[v0 + (lane & 15)];
      bcar[1] = bn[v0 + 16 + (lane & 15)];
      #pragma unroll
      for (int i2 = 0; i2 < 16; i2++) {
        int e = tid + i2 * 256;
        int k = e >> 3, pp = e & 7;
        #pragma unroll
        for (int j = 0; j < 4; j++) {
          __bf16 hi, lo; split2(((const float*)&v[i2])[j], hi, lo);
          sm.l.Bh[pp * 4 + j][k] = hi;
          sm.l.Bl[pp * 4 + j][k] = lo;
        }
      }
    };

    stageW(0);   // logits(0) uses lidx=0

    for (int t = 0; t < TT; t++) {
      const int po = (t & 1) ^ 1, par = t & 1;
      spin_until(&p.cd[t], NCELL);   // barrier also makes staged LDS visible

      const __bf16* hhi = p.h_hi + (size_t)po * BB * HID;
      const __bf16* hlo = p.h_lo + (size_t)po * BB * HID;

      f32x4 acc[2][2] = {};
      #pragma unroll
      for (int ks = 0; ks < 16; ks++) {
        int kk = ks * 32 + (lane >> 4) * 8;
        bf16x8 ah = *(const bf16x8*)(hhi + (size_t)row * HID + kk);
        bf16x8 al = *(const bf16x8*)(hlo + (size_t)row * HID + kk);
        #pragma unroll
        for (int vt = 0; vt < 2; vt++) {
          int rrow = vt * 16 + (lane & 15);
          bf16x8 bh = *(const bf16x8*)&sm.l.Bh[rrow][kk];
          bf16x8 bl = *(const bf16x8*)&sm.l.Bl[rrow][kk];
          acc[vt][0] = __builtin_amdgcn_mfma_f32_16x16x32_bf16(ah, bh, acc[vt][0], 0, 0, 0);
          acc[vt][1] = __builtin_amdgcn_mfma_f32_16x16x32_bf16(ah, bl, acc[vt][1], 0, 0, 0);
          acc[vt][1] = __builtin_amdgcn_mfma_f32_16x16x32_bf16(al, bh, acc[vt][1], 0, 0, 0);
          acc[vt][0] = __builtin_amdgcn_mfma_f32_16x16x32_bf16(al, bl, acc[vt][0], 0, 0, 0);
        }
      }

      float rsum[4] = {0.f, 0.f, 0.f, 0.f};
      unsigned long long rmax[4] = {0ULL, 0ULL, 0ULL, 0ULL};

      #pragma unroll
      for (int vt = 0; vt < 2; vt++) {
        int v = v0 + vt * 16 + (lane & 15);
        if (v < NV) {
          float bb = bcar[vt];
          #pragma unroll
          for (int j = 0; j < 4; j++) {
            int r = wid * 16 + (lane >> 4) * 4 + j;
            float logit = acc[vt][0][j] + acc[vt][1][j] + bb;
            float e = expf(logit);          // no max-subtract: |logit| small
            p.out[(size_t)r * TT * NV + (size_t)t * NV + v] = e;
            rsum[j] += e;
            unsigned long long pk = packkey(logit, v);
            if (pk > rmax[j]) rmax[j] = pk;
          }
        }
      }

      #pragma unroll
      for (int off = 1; off < 16; off <<= 1) {
        #pragma unroll
        for (int j = 0; j < 4; j++) {
          rsum[j] += __shfl_xor(rsum[j], off);
          unsigned long long o = shflxor64(rmax[j], off);
          if (o > rmax[j]) rmax[j] = o;
        }
      }
      if ((lane & 15) == 0) {                 // per-block partials, NO atomics
        #pragma unroll
        for (int j = 0; j < 4; j++) {
          int r = wid * 16 + (lane >> 4) * 4 + j;
          p.psum[(size_t)par * NLOG * BB + (size_t)lb * BB + r] = rsum[j];
          p.pmax[(size_t)par * NLOG * BB + (size_t)lb * BB + r] = rmax[j];
        }
      }
      mark_done(&p.ld[t]);   // barrier also protects LDS before re-staging

      if (t < TT - 1) stageW(t);   // logits(t+1) uses lidx=t; overlaps cell(t+1)
    }
    return;
  }

  // ================= NORM/REDUCE blocks 441..504 (one per row) =============
  if (bid < NORMB + BB) {
    const int r = bid - NORMB;
    for (int t = 0; t < TT; t++) {
      const int par = t & 1;
      spin_until(&p.ld[t], NLOG);

      // tree-reduce 313 per-block partials for row r
      float s = 0.f; unsigned long long m = 0ULL;
      for (int i = tid; i < NLOG; i += 256) {
        s += p.psum[(size_t)par * NLOG * BB + (size_t)i * BB + r];
        unsigned long long v = p.pmax[(size_t)par * NLOG * BB + (size_t)i * BB + r];
        if (v > m) m = v;
      }
      #pragma unroll
      for (int off = 1; off < 64; off <<= 1) {
        s += __shfl_xor(s, off);
        unsigned long long o = shflxor64(m, off);
        if (o > m) m = o;
      }
      if (lane == 0) { red_s[wid] = s; red_m[wid] = m; }
      __syncthreads();
      if (tid == 0) {
        s = red_s[0] + red_s[1] + red_s[2] + red_s[3];
        m = red_m[0];
        if (red_m[1] > m) m = red_m[1];
        if (red_m[2] > m) m = red_m[2];
        if (red_m[3] > m) m = red_m[3];
        p.tok[par * BB + r] = 0xFFFFFFFFu - (unsigned)(m & 0xFFFFFFFFull);
        bcast_inv = 1.0f / s;
        __hip_atomic_fetch_add(&p.rn[t], 1, __ATOMIC_RELEASE, __HIP_MEMORY_SCOPE_AGENT);
      }
      __syncthreads();

      // normalize y[t] row r (off the critical path)
      float inv = bcast_inv;
      float4* y4 = (float4*)(p.out + (size_t)r * TT * NV + (size_t)t * NV);
      for (int i = tid; i < NV / 4; i += 256) {
        float4 v = y4[i];
        v.x *= inv; v.y *= inv; v.z *= inv; v.w *= inv;
        y4[i] = v;
      }
      __syncthreads();   // bcast_inv/red reuse safety for next iteration
    }
    return;
  }
  // blocks 505..511 idle
}

extern "C" void kernel_launch(void* const* d_in, const int* in_sizes, int n_in,
                              void* d_out, int out_size, void* d_ws, size_t ws_size,
                              hipStream_t stream) {
  const float* x     = (const float*)d_in[0];
  const float* h0    = (const float*)d_in[1];
  const float* c0    = (const float*)d_in[2];
  const float* W_hi  = (const float*)d_in[3];
  const float* W_xi  = (const float*)d_in[4];
  const float* b_i   = (const float*)d_in[5];
  const float* W_hf  = (const float*)d_in[6];
  const float* W_xf  = (const float*)d_in[7];
  const float* b_f   = (const float*)d_in[8];
  const float* W_ho  = (const float*)d_in[9];
  const float* W_xo  = (const float*)d_in[10];
  const float* b_o   = (const float*)d_in[11];
  const float* W_hz  = (const float*)d_in[12];
  const float* W_xz  = (const float*)d_in[13];
  const float* b_z   = (const float*)d_in[14];
  const float* W_lin = (const float*)d_in[15];
  const float* b_lin = (const float*)d_in[16];
  const float* emb   = (const float*)d_in[17];

  float* out = (float*)d_out;
  char* ws = (char*)d_ws;
  __bf16* h_hi = (__bf16*)ws;                                    // [2][64][512]
  __bf16* h_lo = (__bf16*)(ws + 131072);                         // [2][64][512]
  float*  c_ws = (float*)(ws + 262144);                          // [64][512]
  int*    ctrs = (int*)(ws + 393216);                            // cd,ld,rn [32]ea
  float*  psum = (float*)(ws + 393728);                          // [2][313][64]
  unsigned long long* pmax = (unsigned long long*)(ws + 553984); // [2][313][64]
  unsigned* tok = (unsigned*)(ws + 874496);                      // [2][64]

  k_init<<<128, 256, 0, stream>>>(h0, c0, h_hi, h_lo, c_ws, ctrs);

  Params P;
  P.x = x; P.emb = emb;
  P.Whi = W_hi; P.Whf = W_hf; P.Who = W_ho; P.Whz = W_hz;
  P.Wxi = W_xi; P.Wxf = W_xf; P.Wxo = W_xo; P.Wxz = W_xz;
  P.bi = b_i; P.bfg = b_f; P.bo = b_o; P.bz = b_z;
  P.W_lin = W_lin; P.b_lin = b_lin;
  P.out = out;
  P.h_hi = h_hi; P.h_lo = h_lo; P.c_ws = c_ws;
  P.psum = psum; P.pmax = pmax; P.tok = tok;
  P.cd = ctrs; P.ld = ctrs + 32; P.rn = ctrs + 64;

  k_main<<<GRID, 256, 0, stream>>>(P);
}

// Round 8
// 1205.405 us; speedup vs baseline: 2.2184x; 1.9089x over previous
//
#include <hip/hip_runtime.h>
#include <hip/hip_bf16.h>
#include <stdint.h>

#define BB 64
#define TT 32
#define HID 512
#define XD  512
#define NV  10000

#define GRID   512
#define NCELL  128
#define VB     32
#define NLOG   313       // ceil(10000/32)
#define LOGB   128       // first logits block
#define NORMB  441       // norm blocks 441..504 (one per batch row)

typedef __bf16 bf16x8 __attribute__((ext_vector_type(8)));
typedef float  f32x4  __attribute__((ext_vector_type(4)));

__device__ inline void split2(float w, __bf16& hi, __bf16& lo) {
  hi = (__bf16)w;
  lo = (__bf16)(w - (float)hi);
}

__device__ inline unsigned long long shflxor64(unsigned long long v, int m) {
  unsigned lo = (unsigned)(v & 0xFFFFFFFFull);
  unsigned hi = (unsigned)(v >> 32);
  lo = __shfl_xor(lo, m);
  hi = __shfl_xor(hi, m);
  return ((unsigned long long)hi << 32) | lo;
}

// monotonic packing of (logit, vocab index); larger u64 = larger logit,
// ties broken toward SMALLER index (matches jnp.argmax first-occurrence).
__device__ inline unsigned long long packkey(float f, int v) {
  unsigned ub = __float_as_uint(f);
  unsigned key = (ub & 0x80000000u) ? ~ub : (ub | 0x80000000u);
  return ((unsigned long long)key << 32) | (unsigned)(0xFFFFFFFFu - (unsigned)v);
}

// ---- coherence-free sync: 8-way line-spread relaxed counters ----
// ctr layout: [3][TT][8][16] ints (each of 8 sub-counters on its own 64B line)
__device__ inline int read8(int* base) {
  int s = 0;
  #pragma unroll
  for (int j = 0; j < 8; j++)
    s += __hip_atomic_load(base + j * 16, __ATOMIC_RELAXED, __HIP_MEMORY_SCOPE_AGENT);
  return s;
}
__device__ inline void spin8(int* base, int target) {
  if (threadIdx.x == 0)
    while (read8(base) < target) __builtin_amdgcn_s_sleep(2);
  __syncthreads();
}
// All cross-block data is written WRITE-THROUGH (relaxed agent atomics), so no
// wbl2/inv is needed: drain stores (vmcnt 0), barrier, then one relaxed bump.
__device__ inline void publish(int* base) {
  asm volatile("s_waitcnt vmcnt(0)" ::: "memory");
  __syncthreads();
  if (threadIdx.x == 0)
    __hip_atomic_fetch_add(base + (blockIdx.x & 7) * 16, 1,
                           __ATOMIC_RELAXED, __HIP_MEMORY_SCOPE_AGENT);
}

struct Params {
  const float *x, *emb;
  const float *Whi, *Whf, *Who, *Whz;
  const float *Wxi, *Wxf, *Wxo, *Wxz;
  const float *bi, *bfg, *bo, *bz;
  const float *W_lin, *b_lin;
  float* out;
  __bf16 *h_hi, *h_lo;         // [TT+1][BB*HID] one buffer per step (write-once)
  float* c_ws;
  float* psum;                 // [2][NLOG][BB]
  unsigned long long* pmax;    // [2][NLOG][BB]
  unsigned* tok;               // [2][BB]
  int* ctr;                    // [3][TT][8][16]
};

struct SMCell { __bf16 Ch[16][1042]; __bf16 Cl[16][1042]; float pre[64][17]; };
struct SMLog  { __bf16 Bh[32][522];  __bf16 Bl[32][522]; };
union SMU { SMCell c; SMLog l; };

__global__ __launch_bounds__(256) void k_init(
    const float* __restrict__ h0, const float* __restrict__ c0,
    __bf16* __restrict__ h_hi, __bf16* __restrict__ h_lo,
    float* __restrict__ c_ws, int* __restrict__ ctrs) {
  int i = blockIdx.x * 256 + threadIdx.x;   // 128 blocks = BB*HID threads
  float h = h0[i];
  __bf16 hi, lo; split2(h, hi, lo);
  h_hi[i] = hi; h_lo[i] = lo;               // buffer 0; kernel-end flush -> LLC
  c_ws[i] = c0[i];
  if (i < 3 * TT * 128) ctrs[i] = 0;        // 12288 ints
}

__global__ __launch_bounds__(256, 2) void k_main(Params p) {
  __shared__ SMU sm;
  __shared__ float red_s[4];
  __shared__ unsigned long long red_m[4];
  __shared__ float bcast_inv;
  const int bid = blockIdx.x, tid = threadIdx.x;
  const int lane = tid & 63, wid = tid >> 6;

  int* cd0 = p.ctr;                  // [TT][128]
  int* ld0 = p.ctr + TT * 128;
  int* rn0 = p.ctr + 2 * TT * 128;

  // ======================= CELL blocks 0..127 =======================
  if (bid < NCELL) {
    const int n0 = bid * 4;
    const float* WH[4] = {p.Whi, p.Whf, p.Who, p.Whz};
    const float* WX[4] = {p.Wxi, p.Wxf, p.Wxo, p.Wxz};

    // one-time stage: 16 rows (gate g, col j) x K=1024 (h:0..511, x:512..1023)
    #pragma unroll
    for (int i2 = 0; i2 < 16; i2++) {
      int e = tid + i2 * 256;          // e = k*4 + g
      int k = e >> 2, g = e & 3;
      const float* src = (k < HID) ? (WH[g] + (size_t)k * HID + n0)
                                   : (WX[g] + (size_t)(k - HID) * HID + n0);
      float4 w = *(const float4*)src;
      #pragma unroll
      for (int j = 0; j < 4; j++) {
        __bf16 hi, lo; split2(((const float*)&w)[j], hi, lo);
        sm.c.Ch[g * 4 + j][k] = hi;
        sm.c.Cl[g * 4 + j][k] = lo;
      }
    }
    __syncthreads();

    const int row  = wid * 16 + (lane & 15);
    const int brow = lane & 15;

    for (int t = 0; t < TT; t++) {
      if (t > 0) spin8(cd0 + (t - 1) * 128, NCELL);   // h[t] fully published

      const __bf16* hr  = p.h_hi + (size_t)t * BB * HID;
      const __bf16* hrl = p.h_lo + (size_t)t * BB * HID;
      __bf16* hw  = p.h_hi + (size_t)(t + 1) * BB * HID;
      __bf16* hwl = p.h_lo + (size_t)(t + 1) * BB * HID;

      f32x4 accA = {0.f, 0.f, 0.f, 0.f};
      f32x4 accB = {0.f, 0.f, 0.f, 0.f};

      // h-part FIRST (needs only cd[t-1]) — overlaps logits/reduce of t-1
      #pragma unroll
      for (int ks = 0; ks < 16; ks++) {
        int kk = ks * 32 + (lane >> 4) * 8;
        bf16x8 ah = *(const bf16x8*)(hr  + (size_t)row * HID + kk);
        bf16x8 al = *(const bf16x8*)(hrl + (size_t)row * HID + kk);
        bf16x8 bh = *(const bf16x8*)&sm.c.Ch[brow][kk];
        bf16x8 bl = *(const bf16x8*)&sm.c.Cl[brow][kk];
        accA = __builtin_amdgcn_mfma_f32_16x16x32_bf16(ah, bh, accA, 0, 0, 0);
        accB = __builtin_amdgcn_mfma_f32_16x16x32_bf16(ah, bl, accB, 0, 0, 0);
        accB = __builtin_amdgcn_mfma_f32_16x16x32_bf16(al, bh, accB, 0, 0, 0);
        accA = __builtin_amdgcn_mfma_f32_16x16x32_bf16(al, bl, accA, 0, 0, 0);
      }

      // token wait only gates the x-part
      const float* xrow;
      if (t == 0) {
        xrow = p.x + (size_t)row * TT * XD;          // x[row][0][:]
      } else {
        spin8(rn0 + (t - 1) * 128, BB);
        unsigned tokv = __hip_atomic_load(&p.tok[((t - 1) & 1) * BB + row],
                                          __ATOMIC_RELAXED, __HIP_MEMORY_SCOPE_AGENT);
        xrow = p.emb + (size_t)tokv * XD;
      }

      #pragma unroll
      for (int ks = 16; ks < 32; ks++) {
        int kk = ks * 32 + (lane >> 4) * 8;          // 512..1016
        const float* xp = xrow + (kk - HID);
        float4 w0 = *(const float4*)(xp);
        float4 w1 = *(const float4*)(xp + 4);
        bf16x8 ah, al;
        #pragma unroll
        for (int j = 0; j < 4; j++) {
          __bf16 hi, lo;
          split2(((const float*)&w0)[j], hi, lo); ah[j] = hi; al[j] = lo;
          split2(((const float*)&w1)[j], hi, lo); ah[4 + j] = hi; al[4 + j] = lo;
        }
        bf16x8 bh = *(const bf16x8*)&sm.c.Ch[brow][kk];
        bf16x8 bl = *(const bf16x8*)&sm.c.Cl[brow][kk];
        accA = __builtin_amdgcn_mfma_f32_16x16x32_bf16(ah, bh, accA, 0, 0, 0);
        accB = __builtin_amdgcn_mfma_f32_16x16x32_bf16(ah, bl, accB, 0, 0, 0);
        accB = __builtin_amdgcn_mfma_f32_16x16x32_bf16(al, bh, accB, 0, 0, 0);
        accA = __builtin_amdgcn_mfma_f32_16x16x32_bf16(al, bl, accA, 0, 0, 0);
      }

      #pragma unroll
      for (int j = 0; j < 4; j++)
        sm.c.pre[wid * 16 + (lane >> 4) * 4 + j][lane & 15] = accA[j] + accB[j];
      __syncthreads();

      {
        int rloc = tid >> 2, q = tid & 3;
        int n = n0 + q;
        float pi = sm.c.pre[rloc][q]      + p.bi[n];
        float pf = sm.c.pre[rloc][4 + q]  + p.bfg[n];
        float pq = sm.c.pre[rloc][8 + q]  + p.bo[n];
        float pz = sm.c.pre[rloc][12 + q] + p.bz[n];
        float ig = 1.f / (1.f + expf(-pi));
        float fg = 1.f / (1.f + expf(-pf));
        float og = 1.f / (1.f + expf(-pq));
        float zg = tanhf(pz);
        float cp = p.c_ws[rloc * HID + n];
        float cn = ig * zg + fg * cp;
        p.c_ws[rloc * HID + n] = cn;
        p.out[(size_t)BB * TT * NV + (size_t)rloc * TT * HID + (size_t)t * HID + n] = cn;
        float hn = og * tanhf(cn);
        __bf16 hh, hl; split2(hn, hh, hl);
        // write-through h[t+1]: pair 2 bf16 into one u32 relaxed agent store
        unsigned hhu = (unsigned)__builtin_bit_cast(unsigned short, hh);
        unsigned hlu = (unsigned)__builtin_bit_cast(unsigned short, hl);
        unsigned hh1 = __shfl_down(hhu, 1);
        unsigned hl1 = __shfl_down(hlu, 1);
        if (!(q & 1)) {
          __hip_atomic_store((unsigned*)(hw + rloc * HID + n), hhu | (hh1 << 16),
                             __ATOMIC_RELAXED, __HIP_MEMORY_SCOPE_AGENT);
          __hip_atomic_store((unsigned*)(hwl + rloc * HID + n), hlu | (hl1 << 16),
                             __ATOMIC_RELAXED, __HIP_MEMORY_SCOPE_AGENT);
        }
      }
      publish(cd0 + t * 128);
    }
    return;
  }

  // ======================= LOGITS blocks 128..440 =======================
  if (bid < NORMB) {
    const int lb = bid - LOGB;
    const int v0 = lb * VB;
    const int row = wid * 16 + (lane & 15);

    float bcar[2];

    auto stageW = [&](int widx) {
      const float* W = p.W_lin + (size_t)widx * HID * NV;
      float4 v[16];
      #pragma unroll
      for (int i2 = 0; i2 < 16; i2++) {
        int e = tid + i2 * 256;          // e = k*8 + pp
        int k = e >> 3, pp = e & 7;
        v[i2] = *(const float4*)(W + (size_t)k * NV + v0 + pp * 4);
      }
      const float* bn = p.b_lin + (size_t)widx * NV;
      bcar[0] = bn[v0 + (lane & 15)];
      bcar[1] = bn[v0 + 16 + (lane & 15)];   // may over-read; masked later
      #pragma unroll
      for (int i2 = 0; i2 < 16; i2++) {
        int e = tid + i2 * 256;
        int k = e >> 3, pp = e & 7;
        #pragma unroll
        for (int j = 0; j < 4; j++) {
          __bf16 hi, lo; split2(((const float*)&v[i2])[j], hi, lo);
          sm.l.Bh[pp * 4 + j][k] = hi;
          sm.l.Bl[pp * 4 + j][k] = lo;
        }
      }
    };

    stageW(0);   // logits(0) uses lidx=0

    for (int t = 0; t < TT; t++) {
      const int par = t & 1;
      spin8(cd0 + t * 128, NCELL);     // h[t+1] published; barrier covers LDS

      const __bf16* hhi = p.h_hi + (size_t)(t + 1) * BB * HID;
      const __bf16* hlo = p.h_lo + (size_t)(t + 1) * BB * HID;

      f32x4 acc[2][2] = {};
      #pragma unroll
      for (int ks = 0; ks < 16; ks++) {
        int kk = ks * 32 + (lane >> 4) * 8;
        bf16x8 ah = *(const bf16x8*)(hhi + (size_t)row * HID + kk);
        bf16x8 al = *(const bf16x8*)(hlo + (size_t)row * HID + kk);
        #pragma unroll
        for (int vt = 0; vt < 2; vt++) {
          int rrow = vt * 16 + (lane & 15);
          bf16x8 bh = *(const bf16x8*)&sm.l.Bh[rrow][kk];
          bf16x8 bl = *(const bf16x8*)&sm.l.Bl[rrow][kk];
          acc[vt][0] = __builtin_amdgcn_mfma_f32_16x16x32_bf16(ah, bh, acc[vt][0], 0, 0, 0);
          acc[vt][1] = __builtin_amdgcn_mfma_f32_16x16x32_bf16(ah, bl, acc[vt][1], 0, 0, 0);
          acc[vt][1] = __builtin_amdgcn_mfma_f32_16x16x32_bf16(al, bh, acc[vt][1], 0, 0, 0);
          acc[vt][0] = __builtin_amdgcn_mfma_f32_16x16x32_bf16(al, bl, acc[vt][0], 0, 0, 0);
        }
      }

      float rsum[4] = {0.f, 0.f, 0.f, 0.f};
      unsigned long long rmax[4] = {0ULL, 0ULL, 0ULL, 0ULL};

      #pragma unroll
      for (int vt = 0; vt < 2; vt++) {
        int v = v0 + vt * 16 + (lane & 15);
        if (v < NV) {
          float bb = bcar[vt];
          #pragma unroll
          for (int j = 0; j < 4; j++) {
            int r = wid * 16 + (lane >> 4) * 4 + j;
            float logit = acc[vt][0][j] + acc[vt][1][j] + bb;
            float e = expf(logit);        // no max-subtract: |logit| small
            __hip_atomic_store(p.out + (size_t)r * TT * NV + (size_t)t * NV + v, e,
                               __ATOMIC_RELAXED, __HIP_MEMORY_SCOPE_AGENT);
            rsum[j] += e;
            unsigned long long pk = packkey(logit, v);
            if (pk > rmax[j]) rmax[j] = pk;
          }
        }
      }

      #pragma unroll
      for (int off = 1; off < 16; off <<= 1) {
        #pragma unroll
        for (int j = 0; j < 4; j++) {
          rsum[j] += __shfl_xor(rsum[j], off);
          unsigned long long o = shflxor64(rmax[j], off);
          if (o > rmax[j]) rmax[j] = o;
        }
      }
      if ((lane & 15) == 0) {           // per-block partials, write-through
        #pragma unroll
        for (int j = 0; j < 4; j++) {
          int r = wid * 16 + (lane >> 4) * 4 + j;
          __hip_atomic_store(&p.psum[(size_t)par * NLOG * BB + (size_t)lb * BB + r],
                             rsum[j], __ATOMIC_RELAXED, __HIP_MEMORY_SCOPE_AGENT);
          __hip_atomic_store(&p.pmax[(size_t)par * NLOG * BB + (size_t)lb * BB + r],
                             rmax[j], __ATOMIC_RELAXED, __HIP_MEMORY_SCOPE_AGENT);
        }
      }
      publish(ld0 + t * 128);

      if (t < TT - 1) stageW(t);   // logits(t+1) uses lidx=t; overlaps cell(t+1)
    }
    return;
  }

  // ================= NORM/REDUCE blocks 441..504 (one per row) =============
  if (bid < NORMB + BB) {
    const int r = bid - NORMB;
    for (int t = 0; t < TT; t++) {
      const int par = t & 1;
      spin8(ld0 + t * 128, NLOG);

      float s = 0.f; unsigned long long m = 0ULL;
      for (int i = tid; i < NLOG; i += 256) {
        s += __hip_atomic_load(&p.psum[(size_t)par * NLOG * BB + (size_t)i * BB + r],
                               __ATOMIC_RELAXED, __HIP_MEMORY_SCOPE_AGENT);
        unsigned long long v =
            __hip_atomic_load(&p.pmax[(size_t)par * NLOG * BB + (size_t)i * BB + r],
                              __ATOMIC_RELAXED, __HIP_MEMORY_SCOPE_AGENT);
        if (v > m) m = v;
      }
      #pragma unroll
      for (int off = 1; off < 64; off <<= 1) {
        s += __shfl_xor(s, off);
        unsigned long long o = shflxor64(m, off);
        if (o > m) m = o;
      }
      if (lane == 0) { red_s[wid] = s; red_m[wid] = m; }
      __syncthreads();
      if (tid == 0) {
        s = red_s[0] + red_s[1] + red_s[2] + red_s[3];
        m = red_m[0];
        if (red_m[1] > m) m = red_m[1];
        if (red_m[2] > m) m = red_m[2];
        if (red_m[3] > m) m = red_m[3];
        __hip_atomic_store(&p.tok[par * BB + r],
                           0xFFFFFFFFu - (unsigned)(m & 0xFFFFFFFFull),
                           __ATOMIC_RELAXED, __HIP_MEMORY_SCOPE_AGENT);
        asm volatile("s_waitcnt vmcnt(0)" ::: "memory");   // tok at LLC first
        __hip_atomic_fetch_add(rn0 + t * 128 + (bid & 7) * 16, 1,
                               __ATOMIC_RELAXED, __HIP_MEMORY_SCOPE_AGENT);
        bcast_inv = 1.0f / s;
      }
      __syncthreads();

      // normalize y[t] row r (off the critical path; addresses write-once)
      float inv = bcast_inv;
      float4* y4 = (float4*)(p.out + (size_t)r * TT * NV + (size_t)t * NV);
      for (int i = tid; i < NV / 4; i += 256) {
        float4 v = y4[i];
        v.x *= inv; v.y *= inv; v.z *= inv; v.w *= inv;
        y4[i] = v;
      }
      __syncthreads();   // red/bcast reuse safety
    }
    return;
  }
  // blocks 505..511 idle
}

extern "C" void kernel_launch(void* const* d_in, const int* in_sizes, int n_in,
                              void* d_out, int out_size, void* d_ws, size_t ws_size,
                              hipStream_t stream) {
  const float* x     = (const float*)d_in[0];
  const float* h0    = (const float*)d_in[1];
  const float* c0    = (const float*)d_in[2];
  const float* W_hi  = (const float*)d_in[3];
  const float* W_xi  = (const float*)d_in[4];
  const float* b_i   = (const float*)d_in[5];
  const float* W_hf  = (const float*)d_in[6];
  const float* W_xf  = (const float*)d_in[7];
  const float* b_f   = (const float*)d_in[8];
  const float* W_ho  = (const float*)d_in[9];
  const float* W_xo  = (const float*)d_in[10];
  const float* b_o   = (const float*)d_in[11];
  const float* W_hz  = (const float*)d_in[12];
  const float* W_xz  = (const float*)d_in[13];
  const float* b_z   = (const float*)d_in[14];
  const float* W_lin = (const float*)d_in[15];
  const float* b_lin = (const float*)d_in[16];
  const float* emb   = (const float*)d_in[17];

  float* out = (float*)d_out;
  char* ws = (char*)d_ws;
  // layout (bytes):
  __bf16* h_hi = (__bf16*)ws;                                     // [33][64*512]
  __bf16* h_lo = (__bf16*)(ws + 2162688);                         // [33][64*512]
  float*  c_ws = (float*)(ws + 4325376);                          // [64*512]
  float*  psum = (float*)(ws + 4456448);                          // [2][313][64]
  unsigned long long* pmax = (unsigned long long*)(ws + 4616704); // [2][313][64]
  unsigned* tok = (unsigned*)(ws + 4937216);                      // [2][64]
  int*    ctrs = (int*)(ws + 4937728);                            // [3][32][8][16]

  k_init<<<128, 256, 0, stream>>>(h0, c0, h_hi, h_lo, c_ws, ctrs);

  Params P;
  P.x = x; P.emb = emb;
  P.Whi = W_hi; P.Whf = W_hf; P.Who = W_ho; P.Whz = W_hz;
  P.Wxi = W_xi; P.Wxf = W_xf; P.Wxo = W_xo; P.Wxz = W_xz;
  P.bi = b_i; P.bfg = b_f; P.bo = b_o; P.bz = b_z;
  P.W_lin = W_lin; P.b_lin = b_lin;
  P.out = out;
  P.h_hi = h_hi; P.h_lo = h_lo; P.c_ws = c_ws;
  P.psum = psum; P.pmax = pmax; P.tok = tok;
  P.ctr = ctrs;

  k_main<<<GRID, 256, 0, stream>>>(P);
}